// Round 1
// baseline (384.718 us; speedup 1.0000x reference)
//
#include <hip/hip_runtime.h>
#include <stdint.h>

#define N 8192
#define DIM 1024
#define EPSF 1e-8f
#define BK 64

typedef __attribute__((ext_vector_type(4))) float f32x4;
typedef __attribute__((ext_vector_type(8))) short s16x8;

// ---- helpers ----
__device__ inline unsigned short f2bf(float f) {
  // round-to-nearest-even fp32 -> bf16 (data is finite/normal)
  unsigned u = __float_as_uint(f);
  unsigned r = (u + 0x7FFFu + ((u >> 16) & 1u)) >> 16;
  return (unsigned short)r;
}

__device__ inline unsigned encf(float f) {
  // monotonic float->u32 (order-preserving for all finite floats)
  unsigned u = __float_as_uint(f);
  return (u & 0x80000000u) ? ~u : (u | 0x80000000u);
}

// ws layout:
//   [0, 16MiB)            : xb   bf16 normalized rows, row-major 8192x1024 (ushort)
//   [16777216, +32KiB)    : invn fp32 per-row 1/max(norm,eps)
//   [16809984, +64KiB)    : keys u64 packed (enc(sim)<<32)|~col
#define XB_OFF   0
#define INV_OFF  16777216
#define KEY_OFF  16809984

// ---------------- kernel 1: normalize + init ----------------
__global__ __launch_bounds__(256)
void k_norm(const float* __restrict__ x, unsigned short* __restrict__ xb,
            float* __restrict__ invn, unsigned long long* __restrict__ keys,
            float* __restrict__ out) {
  int row = blockIdx.x, t = threadIdx.x;
  const float4* xr = (const float4*)(x + (size_t)row * DIM);
  float4 v = xr[t];
  float ss = v.x * v.x + v.y * v.y + v.z * v.z + v.w * v.w;
#pragma unroll
  for (int o = 32; o > 0; o >>= 1) ss += __shfl_down(ss, o, 64);
  __shared__ float red[4];
  __shared__ float sinv;
  if ((t & 63) == 0) red[t >> 6] = ss;
  __syncthreads();
  if (t == 0) {
    float s = red[0] + red[1] + red[2] + red[3];
    float inv = 1.0f / fmaxf(sqrtf(s), EPSF);
    sinv = inv;
    invn[row] = inv;
    keys[row] = 0ull;           // any sim >= -1 encodes > 0
    if (row == 0) out[0] = 0.0f;
  }
  __syncthreads();
  float inv = sinv;
  ushort4 o4;
  o4.x = f2bf(v.x * inv);
  o4.y = f2bf(v.y * inv);
  o4.z = f2bf(v.z * inv);
  o4.w = f2bf(v.w * inv);
  ((ushort4*)(xb + (size_t)row * DIM))[t] = o4;
}

// ---------------- kernel 2: sim GEMM + argmax ----------------
// Upper-triangular block pairs (bi<=bj); each block computes a 128x128 tile of
// X_norm @ X_norm^T with bf16 MFMA, then argmax-reduces along rows AND cols
// (symmetry) into packed u64 keys via atomicMax.
__global__ __launch_bounds__(256)
void k_sim(const unsigned short* __restrict__ xb, unsigned long long* __restrict__ keys) {
  const int bj = blockIdx.x, bi = blockIdx.y;
  if (bj < bi) return;
  __shared__ unsigned short sA[128 * BK];
  __shared__ unsigned short sB[128 * BK];
  const int t = threadIdx.x, lane = t & 63, wv = t >> 6;
  const int wr = wv >> 1, wc = wv & 1;       // wave -> 64x64 quadrant
  const int hi = lane >> 4, lo = lane & 15;
  const int rowBase = bi * 128, colBase = bj * 128;

  const f32x4 fzero = {0.f, 0.f, 0.f, 0.f};
  f32x4 acc[4][4];
#pragma unroll
  for (int i = 0; i < 4; ++i)
#pragma unroll
    for (int j = 0; j < 4; ++j) acc[i][j] = fzero;

  const int sr = t >> 3;   // staging row within 32-row group
  const int sc = t & 7;    // 16B chunk index within a 128B row-slice

  for (int kt = 0; kt < DIM / BK; ++kt) {
    const unsigned short* gA = xb + (size_t)rowBase * DIM + kt * BK;
    const unsigned short* gB = xb + (size_t)colBase * DIM + kt * BK;
#pragma unroll
    for (int it = 0; it < 4; ++it) {
      int r = it * 32 + sr;
      int cs = sc ^ (r & 7);                 // XOR swizzle (chunk granularity)
      s16x8 va = *(const s16x8*)(gA + (size_t)r * DIM + sc * 8);
      s16x8 vb = *(const s16x8*)(gB + (size_t)r * DIM + sc * 8);
      *(s16x8*)(&sA[r * BK + cs * 8]) = va;
      *(s16x8*)(&sB[r * BK + cs * 8]) = vb;
    }
    __syncthreads();
#pragma unroll
    for (int kk = 0; kk < 2; ++kk) {
      s16x8 af[4], bf[4];
#pragma unroll
      for (int mi = 0; mi < 4; ++mi) {
        int r = wr * 64 + mi * 16 + lo;
        int c = (kk * 4 + hi) ^ (r & 7);
        af[mi] = *(const s16x8*)(&sA[r * BK + c * 8]);
      }
#pragma unroll
      for (int ni = 0; ni < 4; ++ni) {
        int r = wc * 64 + ni * 16 + lo;
        int c = (kk * 4 + hi) ^ (r & 7);
        bf[ni] = *(const s16x8*)(&sB[r * BK + c * 8]);
      }
#pragma unroll
      for (int mi = 0; mi < 4; ++mi)
#pragma unroll
        for (int ni = 0; ni < 4; ++ni)
          acc[mi][ni] = __builtin_amdgcn_mfma_f32_16x16x32_bf16(af[mi], bf[ni], acc[mi][ni], 0, 0, 0);
    }
    __syncthreads();
  }

  // ---- epilogue: per-row argmax (C layout: col=lane&15, row=(lane>>4)*4+reg) ----
#pragma unroll
  for (int mi = 0; mi < 4; ++mi) {
#pragma unroll
    for (int reg = 0; reg < 4; ++reg) {
      int grow = rowBase + wr * 64 + mi * 16 + hi * 4 + reg;
      float best = -10.0f;
      int bcol = 0;
#pragma unroll
      for (int ni = 0; ni < 4; ++ni) {
        int gcol = colBase + wc * 64 + ni * 16 + lo;
        float v = acc[mi][ni][reg];
        v = (gcol == grow) ? -10.0f : v;   // mask diagonal
        if (v > best || (v == best && gcol < bcol)) { best = v; bcol = gcol; }
      }
#pragma unroll
      for (int m = 1; m < 16; m <<= 1) {
        float ov = __shfl_xor(best, m, 64);
        int oc = __shfl_xor(bcol, m, 64);
        if (ov > best || (ov == best && oc < bcol)) { best = ov; bcol = oc; }
      }
      if (lo == 0) {
        unsigned long long key = ((unsigned long long)encf(best) << 32) | (unsigned)(~bcol);
        atomicMax(&keys[grow], key);
      }
    }
  }

  // ---- per-col argmax (symmetric contribution), off-diagonal blocks only ----
  if (bi != bj) {
#pragma unroll
    for (int ni = 0; ni < 4; ++ni) {
      int gcol = colBase + wc * 64 + ni * 16 + lo;
      float best = -10.0f;
      int brow = 0;
#pragma unroll
      for (int mi = 0; mi < 4; ++mi)
#pragma unroll
        for (int reg = 0; reg < 4; ++reg) {
          int grow = rowBase + wr * 64 + mi * 16 + hi * 4 + reg;
          float v = acc[mi][ni][reg];
          if (v > best || (v == best && grow < brow)) { best = v; brow = grow; }
        }
#pragma unroll
      for (int m = 16; m < 64; m <<= 1) {
        float ov = __shfl_xor(best, m, 64);
        int oc = __shfl_xor(brow, m, 64);
        if (ov > best || (ov == best && oc < brow)) { best = ov; brow = oc; }
      }
      if (hi == 0) {
        unsigned long long key = ((unsigned long long)encf(best) << 32) | (unsigned)(~brow);
        atomicMax(&keys[gcol], key);
      }
    }
  }
}

// ---------------- kernel 3: exact fp32 distance + loss ----------------
__global__ __launch_bounds__(256)
void k_dist(const float* __restrict__ x, const float* __restrict__ invn,
            const unsigned long long* __restrict__ keys, float* __restrict__ out) {
  int row = blockIdx.x, t = threadIdx.x;
  unsigned long long key = keys[row];
  int nb = (int)(~(unsigned)key);       // decode ~col
  float ia = invn[row], ib = invn[nb];
  float4 a = ((const float4*)(x + (size_t)row * DIM))[t];
  float4 b = ((const float4*)(x + (size_t)nb * DIM))[t];
  float d0 = a.x * ia - b.x * ib + EPSF;
  float d1 = a.y * ia - b.y * ib + EPSF;
  float d2 = a.z * ia - b.z * ib + EPSF;
  float d3 = a.w * ia - b.w * ib + EPSF;
  float ss = d0 * d0 + d1 * d1 + d2 * d2 + d3 * d3;
#pragma unroll
  for (int o = 32; o > 0; o >>= 1) ss += __shfl_down(ss, o, 64);
  __shared__ float red[4];
  if ((t & 63) == 0) red[t >> 6] = ss;
  __syncthreads();
  if (t == 0) {
    float s = red[0] + red[1] + red[2] + red[3];
    float d = sqrtf(s);
    atomicAdd(out, -logf(d + EPSF) * (1.0f / (float)N));
  }
}

extern "C" void kernel_launch(void* const* d_in, const int* in_sizes, int n_in,
                              void* d_out, int out_size, void* d_ws, size_t ws_size,
                              hipStream_t stream) {
  const float* x = (const float*)d_in[0];
  float* out = (float*)d_out;
  char* ws = (char*)d_ws;
  unsigned short* xb = (unsigned short*)(ws + XB_OFF);
  float* invn = (float*)(ws + INV_OFF);
  unsigned long long* keys = (unsigned long long*)(ws + KEY_OFF);

  k_norm<<<N, 256, 0, stream>>>(x, xb, invn, keys, out);
  dim3 g(64, 64);
  k_sim<<<g, 256, 0, stream>>>(xb, keys);
  k_dist<<<N, 256, 0, stream>>>(x, invn, keys, out);
}

// Round 3
// 244.965 us; speedup vs baseline: 1.5705x; 1.5705x over previous
//
#include <hip/hip_runtime.h>
#include <stdint.h>

#define N 8192
#define DIM 1024
#define EPSF 1e-8f
#define BK 64
#define NBLK 64           // 8192/128
#define NTRI 2080         // NBLK*(NBLK+1)/2

typedef __attribute__((ext_vector_type(4))) float f32x4;
typedef __attribute__((ext_vector_type(8))) short s16x8;

// ---- helpers ----
__device__ inline unsigned short f2bf(float f) {
  unsigned u = __float_as_uint(f);
  unsigned r = (u + 0x7FFFu + ((u >> 16) & 1u)) >> 16;
  return (unsigned short)r;
}

__device__ inline unsigned encf(float f) {
  unsigned u = __float_as_uint(f);
  return (u & 0x80000000u) ? ~u : (u | 0x80000000u);
}

// ws layout:
//   [0, 16MiB)       : xb   bf16 normalized rows, row-major 8192x1024 (ushort)
//   [16777216,+32KiB): invn fp32 per-row 1/max(norm,eps)
//   [16809984,+64KiB): keys u64 packed (enc(sim)<<32)|~col
//   [16875520,+32KiB): part fp32 per-row log(dist+eps)
#define XB_OFF   0
#define INV_OFF  16777216
#define KEY_OFF  16809984
#define PART_OFF 16875520

// ---------------- kernel 1: normalize + init ----------------
__global__ __launch_bounds__(256)
void k_norm(const float* __restrict__ x, unsigned short* __restrict__ xb,
            float* __restrict__ invn, unsigned long long* __restrict__ keys) {
  int row = blockIdx.x, t = threadIdx.x;
  const float4* xr = (const float4*)(x + (size_t)row * DIM);
  float4 v = xr[t];
  float ss = v.x * v.x + v.y * v.y + v.z * v.z + v.w * v.w;
#pragma unroll
  for (int o = 32; o > 0; o >>= 1) ss += __shfl_down(ss, o, 64);
  __shared__ float red[4];
  __shared__ float sinv;
  if ((t & 63) == 0) red[t >> 6] = ss;
  __syncthreads();
  if (t == 0) {
    float s = red[0] + red[1] + red[2] + red[3];
    float inv = 1.0f / fmaxf(sqrtf(s), EPSF);
    sinv = inv;
    invn[row] = inv;
    keys[row] = 0ull;           // any sim >= -1 encodes > 0
  }
  __syncthreads();
  float inv = sinv;
  ushort4 o4;
  o4.x = f2bf(v.x * inv);
  o4.y = f2bf(v.y * inv);
  o4.z = f2bf(v.z * inv);
  o4.w = f2bf(v.w * inv);
  ((ushort4*)(xb + (size_t)row * DIM))[t] = o4;
}

// ---------------- kernel 2: sim GEMM + argmax ----------------
// Triangular 1-D grid: block b -> (bi,bj) with bi<=bj. 128x128 bf16 MFMA tile
// of X@X^T; staging via global_load_lds width=16 (linear LDS dest,
// inverse-swizzled global source so fragment reads use XOR swizzle).
__global__ __launch_bounds__(256)
void k_sim(const unsigned short* __restrict__ xb, unsigned long long* __restrict__ keys) {
  int b = blockIdx.x;
  int bi = (int)((129.0f - sqrtf(16641.0f - 8.0f * (float)b)) * 0.5f);
  while ((bi + 1) * (129 - (bi + 1)) / 2 <= b) ++bi;
  while (bi * (129 - bi) / 2 > b) --bi;
  int bj = bi + (b - bi * (129 - bi) / 2);

  __shared__ unsigned short sA[128 * BK];
  __shared__ unsigned short sB[128 * BK];
  const int t = threadIdx.x, lane = t & 63, wv = t >> 6;
  const int wr = wv >> 1, wc = wv & 1;       // wave -> 64x64 quadrant
  const int hi = lane >> 4, lo = lane & 15;
  const int rowBase = bi * 128, colBase = bj * 128;

  const f32x4 fzero = {0.f, 0.f, 0.f, 0.f};
  f32x4 acc[4][4];
#pragma unroll
  for (int i = 0; i < 4; ++i)
#pragma unroll
    for (int j = 0; j < 4; ++j) acc[i][j] = fzero;

  // staging decomposition: wave wv, lane -> rows w8 + rd*32, chunk (lane&7)
  const int w8 = wv * 8 + (lane >> 3);
  const int cch = lane & 7;

  for (int kt = 0; kt < DIM / BK; ++kt) {
    const unsigned short* gA = xb + (size_t)rowBase * DIM + kt * BK;
    const unsigned short* gB = xb + (size_t)colBase * DIM + kt * BK;
#pragma unroll
    for (int rd = 0; rd < 4; ++rd) {
      int r = rd * 32 + w8;
      int c = cch ^ (r & 7);                 // inverse swizzle on SOURCE
      __builtin_amdgcn_global_load_lds(
          (const __attribute__((address_space(1))) void*)(gA + (size_t)r * DIM + c * 8),
          (__attribute__((address_space(3))) void*)(&sA[rd * 2048 + wv * 512]),
          16, 0, 0);
      __builtin_amdgcn_global_load_lds(
          (const __attribute__((address_space(1))) void*)(gB + (size_t)r * DIM + c * 8),
          (__attribute__((address_space(3))) void*)(&sB[rd * 2048 + wv * 512]),
          16, 0, 0);
    }
    __syncthreads();                         // drains vmcnt(0): tiles staged
#pragma unroll
    for (int kk = 0; kk < 2; ++kk) {
      s16x8 af[4], bf[4];
#pragma unroll
      for (int mi = 0; mi < 4; ++mi) {
        int r = wr * 64 + mi * 16 + lo;
        int c = (kk * 4 + hi) ^ (r & 7);
        af[mi] = *(const s16x8*)(&sA[r * BK + c * 8]);
      }
#pragma unroll
      for (int ni = 0; ni < 4; ++ni) {
        int r = wc * 64 + ni * 16 + lo;
        int c = (kk * 4 + hi) ^ (r & 7);
        bf[ni] = *(const s16x8*)(&sB[r * BK + c * 8]);
      }
#pragma unroll
      for (int mi = 0; mi < 4; ++mi)
#pragma unroll
        for (int ni = 0; ni < 4; ++ni)
          acc[mi][ni] = __builtin_amdgcn_mfma_f32_16x16x32_bf16(af[mi], bf[ni], acc[mi][ni], 0, 0, 0);
    }
    __syncthreads();
  }

  // ---- per-row argmax (C layout: col=lane&15, row=(lane>>4)*4+reg) ----
#pragma unroll
  for (int mi = 0; mi < 4; ++mi) {
#pragma unroll
    for (int reg = 0; reg < 4; ++reg) {
      int grow = rowBase + wr * 64 + mi * 16 + hi * 4 + reg;
      float best = -10.0f;
      int bcol = 0;
#pragma unroll
      for (int ni = 0; ni < 4; ++ni) {
        int gcol = colBase + wc * 64 + ni * 16 + lo;
        float v = acc[mi][ni][reg];
        v = (gcol == grow) ? -10.0f : v;   // mask diagonal
        if (v > best || (v == best && gcol < bcol)) { best = v; bcol = gcol; }
      }
#pragma unroll
      for (int m = 1; m < 16; m <<= 1) {
        float ov = __shfl_xor(best, m, 64);
        int oc = __shfl_xor(bcol, m, 64);
        if (ov > best || (ov == best && oc < bcol)) { best = ov; bcol = oc; }
      }
      if (lo == 0) {
        unsigned long long key = ((unsigned long long)encf(best) << 32) | (unsigned)(~bcol);
        atomicMax(&keys[grow], key);
      }
    }
  }

  // ---- per-col argmax (symmetric contribution), off-diagonal blocks only ----
  if (bi != bj) {
#pragma unroll
    for (int ni = 0; ni < 4; ++ni) {
      int gcol = colBase + wc * 64 + ni * 16 + lo;
      float best = -10.0f;
      int brow = 0;
#pragma unroll
      for (int mi = 0; mi < 4; ++mi)
#pragma unroll
        for (int reg = 0; reg < 4; ++reg) {
          int grow = rowBase + wr * 64 + mi * 16 + hi * 4 + reg;
          float v = acc[mi][ni][reg];
          if (v > best || (v == best && grow < brow)) { best = v; brow = grow; }
        }
#pragma unroll
      for (int m = 16; m < 64; m <<= 1) {
        float ov = __shfl_xor(best, m, 64);
        int oc = __shfl_xor(brow, m, 64);
        if (ov > best || (ov == best && oc < brow)) { best = ov; brow = oc; }
      }
      if (hi == 0) {
        unsigned long long key = ((unsigned long long)encf(best) << 32) | (unsigned)(~brow);
        atomicMax(&keys[gcol], key);
      }
    }
  }
}

// ---------------- kernel 3: exact fp32 distance -> per-row partial ----------------
__global__ __launch_bounds__(256)
void k_dist(const float* __restrict__ x, const float* __restrict__ invn,
            const unsigned long long* __restrict__ keys, float* __restrict__ part) {
  int row = blockIdx.x, t = threadIdx.x;
  unsigned long long key = keys[row];
  int nb = (int)(~(unsigned)key);       // decode ~col
  float ia = invn[row], ib = invn[nb];
  float4 a = ((const float4*)(x + (size_t)row * DIM))[t];
  float4 b = ((const float4*)(x + (size_t)nb * DIM))[t];
  float d0 = a.x * ia - b.x * ib + EPSF;
  float d1 = a.y * ia - b.y * ib + EPSF;
  float d2 = a.z * ia - b.z * ib + EPSF;
  float d3 = a.w * ia - b.w * ib + EPSF;
  float ss = d0 * d0 + d1 * d1 + d2 * d2 + d3 * d3;
#pragma unroll
  for (int o = 32; o > 0; o >>= 1) ss += __shfl_down(ss, o, 64);
  __shared__ float red[4];
  if ((t & 63) == 0) red[t >> 6] = ss;
  __syncthreads();
  if (t == 0) {
    float s = red[0] + red[1] + red[2] + red[3];
    part[row] = logf(sqrtf(s) + EPSF);
  }
}

// ---------------- kernel 4: final reduce (no atomics) ----------------
__global__ __launch_bounds__(1024)
void k_final(const float* __restrict__ part, float* __restrict__ out) {
  int t = threadIdx.x;
  float s = 0.0f;
#pragma unroll
  for (int i = 0; i < N / 1024; ++i) s += part[t + i * 1024];
#pragma unroll
  for (int o = 32; o > 0; o >>= 1) s += __shfl_down(s, o, 64);
  __shared__ float red[16];
  if ((t & 63) == 0) red[t >> 6] = s;
  __syncthreads();
  if (t == 0) {
    float tot = 0.0f;
#pragma unroll
    for (int i = 0; i < 16; ++i) tot += red[i];
    out[0] = -tot / (float)N;
  }
}

extern "C" void kernel_launch(void* const* d_in, const int* in_sizes, int n_in,
                              void* d_out, int out_size, void* d_ws, size_t ws_size,
                              hipStream_t stream) {
  const float* x = (const float*)d_in[0];
  float* out = (float*)d_out;
  char* ws = (char*)d_ws;
  unsigned short* xb = (unsigned short*)(ws + XB_OFF);
  float* invn = (float*)(ws + INV_OFF);
  unsigned long long* keys = (unsigned long long*)(ws + KEY_OFF);
  float* part = (float*)(ws + PART_OFF);

  k_norm<<<N, 256, 0, stream>>>(x, xb, invn, keys);
  k_sim<<<NTRI, 256, 0, stream>>>(xb, keys);
  k_dist<<<N, 256, 0, stream>>>(x, invn, keys, part);
  k_final<<<1, 1024, 0, stream>>>(part, out);
}